// Round 4
// baseline (359.480 us; speedup 1.0000x reference)
//
#include <hip/hip_runtime.h>

// LSTM cell fused, round 4: 8192 x 4096 x 2048 bf16 GEMM, 128x128 tile, BK=64.
// Gate interleave chosen so each wave's 4 nt-fragments are the 4 gates of the
// SAME 16 hidden cols: cat-col = n_outer*128 + wc*64 + gate*16 + n_inner16.
// -> epilogue is fully in-register (no LDS exchange, no extra barriers).
// Nontemporal c_prev/h/c IO keeps A/Wt L2-resident.

#define BDIM 8192
#define KDIM 2048
#define NDIM 1024
#define NCAT 4096

typedef __bf16 bf16x8 __attribute__((ext_vector_type(8)));
typedef __bf16 bf16x4 __attribute__((ext_vector_type(4)));
typedef float  f32x4  __attribute__((ext_vector_type(4)));

__device__ __forceinline__ void async_cp16(const void* g, void* l) {
    __builtin_amdgcn_global_load_lds((__attribute__((address_space(1))) void*)g,
                                     (__attribute__((address_space(3))) void*)l,
                                     16, 0, 0);
}

__device__ __forceinline__ float sigm(float x) { return 1.f / (1.f + __expf(-x)); }
__device__ __forceinline__ float tanh_fast(float x) { return 1.f - 2.f / (1.f + __expf(2.f * x)); }

// ---------------- merged prep: A pack + weight transpose ----------------
// blocks [0, 8192): A = bf16([Z | h_prev]), 8 elems (16B store) per thread.
// blocks [8192, 16384): Wt[catrow][k] = bf16(W_gate[k][n]), 32x32 tiles,
//   catrow = (n>>5)*128 + ((n>>4)&1)*64 + gate*16 + (n&15).
__global__ void prep_kernel(const float* __restrict__ Z, const float* __restrict__ H,
                            const float* __restrict__ Wi, const float* __restrict__ Wf,
                            const float* __restrict__ Wo, const float* __restrict__ Wg,
                            __bf16* __restrict__ A, __bf16* __restrict__ Wt) {
    __shared__ float t[32][33];
    int bid = blockIdx.x;
    if (bid < 8192) {
        int idx = bid * 256 + threadIdx.x;    // one 8-elem group
        int row = idx >> 8;                   // 256 octs per 2048-col row
        int q   = idx & 255;
        const float* src = (q < 128) ? (Z + (size_t)row * 1024 + q * 8)
                                     : (H + (size_t)row * 1024 + (q - 128) * 8);
        float4 v0 = ((const float4*)src)[0];
        float4 v1 = ((const float4*)src)[1];
        bf16x8 o = { (__bf16)v0.x, (__bf16)v0.y, (__bf16)v0.z, (__bf16)v0.w,
                     (__bf16)v1.x, (__bf16)v1.y, (__bf16)v1.z, (__bf16)v1.w };
        ((bf16x8*)A)[idx] = o;
    } else {
        int id  = bid - 8192;
        int g   = id >> 11;                   // 2048 blocks per gate
        int rem = id & 2047;
        int k0  = (rem & 63) * 32;
        int n0  = (rem >> 6) * 32;
        const float* W = (g == 0) ? Wi : (g == 1) ? Wf : (g == 2) ? Wo : Wg;
        int c = threadIdx.x & 31, r8 = threadIdx.x >> 5;
        #pragma unroll
        for (int j = 0; j < 4; ++j) {
            int r = r8 + j * 8;
            t[r][c] = W[(size_t)(k0 + r) * NDIM + (n0 + c)];
        }
        __syncthreads();
        #pragma unroll
        for (int j = 0; j < 4; ++j) {
            int r = r8 + j * 8;   // hid col = n0 + r
            size_t catrow = (size_t)(n0 >> 5) * 128 + ((r >> 4) & 1) * 64 + g * 16 + (r & 15);
            Wt[catrow * KDIM + (k0 + c)] = (__bf16)t[c][r];
        }
    }
}

// ---------------- 128x128 GEMM + in-register LSTM epilogue ----------------
// 256 threads = 4 waves; wave (wr,wc) owns 64x64 quadrant, 4x4 frags of
// mfma 16x16x32 bf16. BK=64 = two conflict-free BK=32 half-stages.
// LDS 32KB: As/Bs each 2 x [128 x 32] bf16, XOR-chunk swizzle (0 conflicts).
// nt = gate (i,f,o,g); lane's col = bx*32 + wc*16 + l15 for ALL nt.
__global__ __launch_bounds__(256, 4)
void lstm_gemm_kernel(const __bf16* __restrict__ A, const __bf16* __restrict__ Wt,
                      const float* __restrict__ b_i, const float* __restrict__ b_f,
                      const float* __restrict__ b_o, const float* __restrict__ b_g,
                      const float* __restrict__ c_prev, float* __restrict__ out) {
    __shared__ char smem[32768];
    __bf16* As = (__bf16*)smem;               // 16 KB (2 x 8KB halves)
    __bf16* Bs = (__bf16*)(smem + 16384);     // 16 KB

    const int tid  = threadIdx.x;
    const int wave = tid >> 6;
    const int lane = tid & 63;
    const int wr = wave >> 1, wc = wave & 1;
    const int bx = blockIdx.x;
    const int m0 = blockIdx.y * 128;
    const int ncat0 = bx * 128;

    // staging: group g = wave*2+i covers rows [g*16, g*16+16) of one half;
    // lane l -> row g*16 + (l>>2), global chunk (l&3)^((l>>3)&3), LDS dense.
    const int srow   = lane >> 2;
    const int schunk = (lane & 3) ^ ((lane >> 3) & 3);
    const __bf16* Ag[2]; __bf16* Al[2];
    const __bf16* Bg[2]; __bf16* Bl[2];
    #pragma unroll
    for (int i = 0; i < 2; ++i) {
        int grp = wave * 2 + i;
        Ag[i] = A  + (size_t)(m0    + grp * 16 + srow) * KDIM + schunk * 8;
        Bg[i] = Wt + (size_t)(ncat0 + grp * 16 + srow) * KDIM + schunk * 8;
        Al[i] = As + grp * 512;
        Bl[i] = Bs + grp * 512;
    }

    // fragment geometry: A[m=l15][k=quad*8+j], swizzled chunk sel
    const int l15  = lane & 15;
    const int quad = lane >> 4;
    const int ksw  = (quad ^ ((l15 >> 1) & 3)) * 8;
    int aoff[4], boff[4];
    #pragma unroll
    for (int t = 0; t < 4; ++t) {
        aoff[t] = (wr * 64 + t * 16 + l15) * 32 + ksw;
        boff[t] = (wc * 64 + t * 16 + l15) * 32 + ksw;
    }

    f32x4 acc[4][4];
    #pragma unroll
    for (int i = 0; i < 4; ++i)
        #pragma unroll
        for (int j = 0; j < 4; ++j) acc[i][j] = (f32x4){0.f, 0.f, 0.f, 0.f};

    for (int k0 = 0; k0 < KDIM; k0 += 64) {
        #pragma unroll
        for (int h = 0; h < 2; ++h)
            #pragma unroll
            for (int i = 0; i < 2; ++i) {
                async_cp16(Ag[i] + k0 + h * 32, Al[i] + h * 4096);
                async_cp16(Bg[i] + k0 + h * 32, Bl[i] + h * 4096);
            }
        __syncthreads();

        #pragma unroll
        for (int h = 0; h < 2; ++h) {
            bf16x8 af[4], bfr[4];
            #pragma unroll
            for (int t = 0; t < 4; ++t) af[t]  = *(const bf16x8*)(As + h * 4096 + aoff[t]);
            #pragma unroll
            for (int t = 0; t < 4; ++t) bfr[t] = *(const bf16x8*)(Bs + h * 4096 + boff[t]);
            #pragma unroll
            for (int mt = 0; mt < 4; ++mt)
                #pragma unroll
                for (int nt = 0; nt < 4; ++nt)
                    acc[mt][nt] = __builtin_amdgcn_mfma_f32_16x16x32_bf16(af[mt], bfr[nt], acc[mt][nt], 0, 0, 0);
        }
        __syncthreads();
    }

    // --- fully in-register epilogue: nt = gate, col shared across nt ---
    const int col = bx * 32 + wc * 16 + l15;
    const float b0 = b_i[col], b1 = b_f[col], b2 = b_o[col], b3 = b_g[col];
    float* outC = out + (size_t)BDIM * NDIM;

    #pragma unroll
    for (int mt = 0; mt < 4; ++mt) {
        const size_t base = (size_t)(m0 + wr * 64 + mt * 16 + quad * 4) * NDIM + col;
        float cp[4];
        #pragma unroll
        for (int r = 0; r < 4; ++r)
            cp[r] = __builtin_nontemporal_load(c_prev + base + (size_t)r * NDIM);
        #pragma unroll
        for (int r = 0; r < 4; ++r) {
            float gi = sigm(acc[mt][0][r] + b0);
            float gf = sigm(acc[mt][1][r] + b1);
            float go = sigm(acc[mt][2][r] + b2);
            float gg = tanh_fast(acc[mt][3][r] + b3);
            float cv = gf * cp[r] + gi * gg;
            float hv = go * tanh_fast(cv);
            size_t pos = base + (size_t)r * NDIM;
            __builtin_nontemporal_store(hv, out + pos);
            __builtin_nontemporal_store(cv, outC + pos);
        }
    }
}

extern "C" void kernel_launch(void* const* d_in, const int* in_sizes, int n_in,
                              void* d_out, int out_size, void* d_ws, size_t ws_size,
                              hipStream_t stream) {
    const float* Z  = (const float*)d_in[0];
    const float* H  = (const float*)d_in[1];
    const float* Cp = (const float*)d_in[2];
    const float* Wi = (const float*)d_in[3];
    const float* bi = (const float*)d_in[4];
    const float* Wf = (const float*)d_in[5];
    const float* bf = (const float*)d_in[6];
    const float* Wo = (const float*)d_in[7];
    const float* bo = (const float*)d_in[8];
    const float* Wg = (const float*)d_in[9];
    const float* bg = (const float*)d_in[10];

    __bf16* Acomb = (__bf16*)d_ws;                              // 32 MB
    __bf16* Wt    = (__bf16*)((char*)d_ws + (size_t)33554432);  // 16 MB

    prep_kernel<<<8192 + 8192, 256, 0, stream>>>(Z, H, Wi, Wf, Wo, Wg, Acomb, Wt);
    lstm_gemm_kernel<<<dim3(NCAT / 128, BDIM / 128), 256, 0, stream>>>(
        Acomb, Wt, bi, bf, bo, bg, Cp, (float*)d_out);
}